// Round 13
// baseline (132.338 us; speedup 1.0000x reference)
//
#include <hip/hip_runtime.h>
#include <hip/hip_bf16.h>

typedef __attribute__((ext_vector_type(8))) short short8;
typedef __attribute__((ext_vector_type(4))) float f32x4;
typedef __attribute__((ext_vector_type(4))) unsigned short ushort4v;
typedef unsigned short u16;
typedef unsigned int u32;

#define MFMA32(a, b, c) __builtin_amdgcn_mfma_f32_16x16x32_bf16((a), (b), (c), 0, 0, 0)

__device__ __forceinline__ u16 f2bf(float f) {
    union { float f; u32 u; } v; v.f = f;
    u32 r = v.u + 0x7FFFu + ((v.u >> 16) & 1u);   // RNE
    return (u16)(r >> 16);
}
__device__ __forceinline__ u32 pack2(float a, float b) {
    return ((u32)f2bf(b) << 16) | (u32)f2bf(a);
}

// ---- ws W^T: ws[m][n][c] = bf16(Wm[c][n])  (R10-verified) ----
__global__ void prep_w(const float* __restrict__ Wq, const float* __restrict__ Wk,
                       const float* __restrict__ Wv, u16* __restrict__ ws)
{
    const int bid = blockIdx.x;          // 0..47
    const int m   = bid >> 4;
    const int seg = bid & 15;
    const int n   = threadIdx.x & 63;
    const int c   = seg * 16 + (threadIdx.x >> 6);
    const float* W = (m == 0) ? Wq : (m == 1) ? Wk : Wv;
    ws[m * 16384 + n * 256 + c] = f2bf(W[c * 64 + n]);
}

// R10-verified attention tile: swapped QK^T (A=k natural rows, B=q), per-lane
// scalar online softmax, bpermute-built PV B-frag. Zero LDS scratch, zero waits.
__device__ __forceinline__ void attn_tile(int tile, int lr, int lg, const int* adr,
                                          const short8* qf,           // [2]
                                          const u16 (*lk)[72],
                                          const u16 (*lvT)[264],
                                          const float* mb, float* ob)
{
    const int nst  = tile + 1;
    const int t_my = 16 * tile + lr;

    float m_ = -1e30f, ls = 0.f;
    f32x4 O[4];
    #pragma unroll
    for (int ht = 0; ht < 4; ++ht) O[ht] = (f32x4){0.f, 0.f, 0.f, 0.f};

    for (int c2 = 0; 2 * c2 < nst; ++c2) {
        // dropout masks early (fly under QK + softmax)
        f32x4 md0 = *(const f32x4*)&mb[(size_t)t_my * 256 + 32 * c2 + 4 * lg];
        f32x4 md1 = *(const f32x4*)&mb[(size_t)t_my * 256 + 32 * c2 + 16 + 4 * lg];

        // QK^T swapped: S[t=lr-col][s = 32c2 + 16sl + 4lg + j]
        f32x4 S0, S1;
        {
            const u16* kr = &lk[16 * (2 * c2) + lr][0];
            short8 kf0 = *(const short8*)&kr[8 * lg];
            short8 kf1 = *(const short8*)&kr[32 + 8 * lg];
            f32x4 a = (f32x4){0.f, 0.f, 0.f, 0.f};
            a = MFMA32(kf0, qf[0], a);
            a = MFMA32(kf1, qf[1], a);
            S0 = a;
        }
        {
            const u16* kr = &lk[16 * (2 * c2 + 1) + lr][0];
            short8 kf0 = *(const short8*)&kr[8 * lg];
            short8 kf1 = *(const short8*)&kr[32 + 8 * lg];
            f32x4 a = (f32x4){0.f, 0.f, 0.f, 0.f};
            a = MFMA32(kf0, qf[0], a);
            a = MFMA32(kf1, qf[1], a);
            S1 = a;
        }

        // scale + causal + chunk max (scalar per lane)
        float cm = m_;
        #pragma unroll
        for (int j = 0; j < 4; ++j) {
            const int sg0 = 32 * c2 + 4 * lg + j;
            const int sg1 = sg0 + 16;
            float L0 = (sg0 <= t_my) ? S0[j] * 0.125f : -1e30f;
            float L1 = (sg1 <= t_my) ? S1[j] * 0.125f : -1e30f;
            S0[j] = L0; S1[j] = L1;
            cm = fmaxf(cm, fmaxf(L0, L1));
        }
        cm = fmaxf(cm, __shfl_xor(cm, 16, 64));
        cm = fmaxf(cm, __shfl_xor(cm, 32, 64));

        const float fs = exp2f((m_ - cm) * 1.44269504f);   // 0 on first chunk
        m_ = cm;

        float cs = 0.f;
        #pragma unroll
        for (int j = 0; j < 4; ++j) {
            float p0 = exp2f((S0[j] - cm) * 1.44269504f);
            float p1 = exp2f((S1[j] - cm) * 1.44269504f);
            S0[j] = p0; S1[j] = p1;
            cs += p0 + p1;
        }
        cs += __shfl_xor(cs, 16, 64);
        cs += __shfl_xor(cs, 32, 64);
        ls = ls * fs + cs;
        #pragma unroll
        for (int ht = 0; ht < 4; ++ht) O[ht] *= fs;

        // dropout (unnormalized P), pack, lane-transpose to PV B-frag
        #pragma unroll
        for (int j = 0; j < 4; ++j) {
            S0[j] = (md0[j] >= 0.25f) ? S0[j] : 0.f;
            S1[j] = (md1[j] >= 0.25f) ? S1[j] : 0.f;
        }
        u32 pk0[2], pk1[2];
        pk0[0] = pack2(S0[0], S0[1]); pk0[1] = pack2(S0[2], S0[3]);
        pk1[0] = pack2(S1[0], S1[1]); pk1[1] = pack2(S1[2], S1[3]);
        union { u32 u[4]; short8 s; } pf;
        #pragma unroll
        for (int e = 0; e < 4; ++e) {
            u32 ca = (u32)__builtin_amdgcn_ds_bpermute(adr[e], (int)pk0[e & 1]);
            u32 cb = (u32)__builtin_amdgcn_ds_bpermute(adr[e], (int)pk1[e & 1]);
            pf.u[e] = (lg >> 1) ? cb : ca;
        }

        #pragma unroll
        for (int ht = 0; ht < 4; ++ht) {
            short8 vf = *(const short8*)&lvT[16 * ht + lr][32 * c2 + 8 * lg];
            O[ht] = MFMA32(vf, pf.s, O[ht]);
        }
    }

    // normalize + store
    const float rf = 1.33333333333f / ls;    // (1/sum) * 1/(1-0.25)
    #pragma unroll
    for (int ht = 0; ht < 4; ++ht) {
        f32x4 o = O[ht] * rf;
        *(f32x4*)&ob[(size_t)t_my * 64 + 16 * ht + 4 * lg] = o;
    }
}

// One 512-thread block per batch; wave w owns t-tiles {w, 15-w} (9 chunks each).
// W^T frags read directly from L2-hot ws (no wt LDS, no staging barriers).
// LDS = 70656 B -> 2 blocks/CU (16 waves); launch_bounds(512,4) -> 128-reg cap,
// structured to fit (proj peak ~95, attention ~65). ONE barrier total.
__global__ __launch_bounds__(512, 4)
void attn_head_fused(const float* __restrict__ x,
                     const float* __restrict__ dmask,
                     float* __restrict__ out,
                     const u16* __restrict__ ws)
{
    __shared__ __align__(16) u16 lk[256][72];     // k [s][h]   36864 B
    __shared__ __align__(16) u16 lvT[64][264];    // v^T [h][s] 33792 B

    const int b   = blockIdx.x;
    const int tid = threadIdx.x;
    const int w   = tid >> 6;
    const int l   = tid & 63;
    const int lr  = l & 15;
    const int lg  = l >> 4;

    const float* xb = x + (size_t)b * 65536;

    // bpermute transpose addresses (R10-verified; shared by qf build and PV)
    int adr[4];
    #pragma unroll
    for (int e = 0; e < 4; ++e) {
        const int lgp = ((8 * lg + 2 * e) & 15) >> 2;
        adr[e] = 4 * (lr + 16 * lgp);
    }

    short8 qf[2][2];   // [pass][ks]

    // ---- two-pass projection: pass 0 -> tile w, pass 1 -> tile 15-w ----
    #pragma unroll
    for (int P = 0; P < 2; ++P) {
        const int Tb = P ? 16 * (15 - w) : 16 * w;

        // x A-fragments: A[row=lr][k=32ks+8lg+i]
        short8 af[8];
        {
            const float* xr = xb + (size_t)(Tb + lr) * 256 + lg * 8;
            #pragma unroll
            for (int ks = 0; ks < 8; ++ks) {
                f32x4 a0 = *(const f32x4*)(xr + ks * 32);
                f32x4 a1 = *(const f32x4*)(xr + ks * 32 + 4);
                short8 f;
                f[0] = (short)f2bf(a0[0]); f[1] = (short)f2bf(a0[1]);
                f[2] = (short)f2bf(a0[2]); f[3] = (short)f2bf(a0[3]);
                f[4] = (short)f2bf(a1[0]); f[5] = (short)f2bf(a1[1]);
                f[6] = (short)f2bf(a1[2]); f[7] = (short)f2bf(a1[3]);
                af[ks] = f;
            }
        }

        f32x4 acc[4];

        // ---- k projection (normal operands) -> lk ----
        {
            const u16* wsk = ws + 16384;
            #pragma unroll
            for (int nj = 0; nj < 4; ++nj) acc[nj] = (f32x4){0.f, 0.f, 0.f, 0.f};
            #pragma unroll
            for (int ks = 0; ks < 8; ++ks)
                #pragma unroll
                for (int nj = 0; nj < 4; ++nj) {
                    short8 bf = *(const short8*)&wsk[(16 * nj + lr) * 256 + 32 * ks + 8 * lg];
                    acc[nj] = MFMA32(af[ks], bf, acc[nj]);
                }
            #pragma unroll
            for (int nj = 0; nj < 4; ++nj) {
                const int n = 16 * nj + lr;
                #pragma unroll
                for (int j = 0; j < 4; ++j)
                    lk[Tb + 4 * lg + j][n] = f2bf(acc[nj][j]);
            }
        }

        // ---- v projection (normal operands) -> lvT ----
        {
            const u16* wsv = ws + 32768;
            #pragma unroll
            for (int nj = 0; nj < 4; ++nj) acc[nj] = (f32x4){0.f, 0.f, 0.f, 0.f};
            #pragma unroll
            for (int ks = 0; ks < 8; ++ks)
                #pragma unroll
                for (int nj = 0; nj < 4; ++nj) {
                    short8 bf = *(const short8*)&wsv[(16 * nj + lr) * 256 + 32 * ks + 8 * lg];
                    acc[nj] = MFMA32(af[ks], bf, acc[nj]);
                }
            const int s0 = Tb + 4 * lg;
            #pragma unroll
            for (int nj = 0; nj < 4; ++nj) {
                ushort4v pk;
                pk[0] = f2bf(acc[nj][0]); pk[1] = f2bf(acc[nj][1]);
                pk[2] = f2bf(acc[nj][2]); pk[3] = f2bf(acc[nj][3]);
                *(ushort4v*)&lvT[16 * nj + lr][s0] = pk;
            }
        }

        // ---- q projection (SWAPPED) -> per-lane q[t=lr][h], bpermute to B-frags ----
        {
            #pragma unroll
            for (int nj = 0; nj < 4; ++nj) acc[nj] = (f32x4){0.f, 0.f, 0.f, 0.f};
            #pragma unroll
            for (int ks = 0; ks < 8; ++ks)
                #pragma unroll
                for (int nj = 0; nj < 4; ++nj) {
                    short8 bf = *(const short8*)&ws[(16 * nj + lr) * 256 + 32 * ks + 8 * lg];
                    acc[nj] = MFMA32(bf, af[ks], acc[nj]);   // A=W^T, B=x
                }
            u32 qk[4][2];
            #pragma unroll
            for (int nj = 0; nj < 4; ++nj) {
                qk[nj][0] = pack2(acc[nj][0], acc[nj][1]);
                qk[nj][1] = pack2(acc[nj][2], acc[nj][3]);
            }
            union { u32 u[4]; short8 s; } q0, q1;
            #pragma unroll
            for (int e = 0; e < 4; ++e) {
                u32 a0 = (u32)__builtin_amdgcn_ds_bpermute(adr[e], (int)qk[0][e & 1]);
                u32 a1 = (u32)__builtin_amdgcn_ds_bpermute(adr[e], (int)qk[1][e & 1]);
                q0.u[e] = (lg >> 1) ? a1 : a0;
                u32 b0 = (u32)__builtin_amdgcn_ds_bpermute(adr[e], (int)qk[2][e & 1]);
                u32 b1 = (u32)__builtin_amdgcn_ds_bpermute(adr[e], (int)qk[3][e & 1]);
                q1.u[e] = (lg >> 1) ? b1 : b0;
            }
            qf[P][0] = q0.s; qf[P][1] = q1.s;
        }
    }

    __syncthreads();   // lk, lvT visible — the ONLY barrier

    // ---- attention: two balanced tiles per wave, waves fully desynced ----
    const float* mb = dmask + (size_t)b * 65536;
    float* ob = out + (size_t)b * 16384;

    attn_tile(w,      lr, lg, adr, qf[0], lk, lvT, mb, ob);
    attn_tile(15 - w, lr, lg, adr, qf[1], lk, lvT, mb, ob);
}

extern "C" void kernel_launch(void* const* d_in, const int* in_sizes, int n_in,
                              void* d_out, int out_size, void* d_ws, size_t ws_size,
                              hipStream_t stream) {
    const float* x  = (const float*)d_in[0];
    const float* Wq = (const float*)d_in[1];
    const float* Wk = (const float*)d_in[2];
    const float* Wv = (const float*)d_in[3];
    const float* dm = (const float*)d_in[4];
    float* outp     = (float*)d_out;
    u16* wsp        = (u16*)d_ws;    // needs 98304 B

    if (ws_size < (size_t)98304) return;   // fail-visible, no OOB writes

    prep_w<<<dim3(48), dim3(1024), 0, stream>>>(Wq, Wk, Wv, wsp);
    attn_head_fused<<<dim3(512), dim3(512), 0, stream>>>(x, dm, outp, wsp);
}

// Round 14
// 58.043 us; speedup vs baseline: 2.2800x; 2.2800x over previous
//
#include <hip/hip_runtime.h>
#include <hip/hip_bf16.h>

typedef __attribute__((ext_vector_type(8))) short short8;
typedef __attribute__((ext_vector_type(4))) float f32x4;
typedef __attribute__((ext_vector_type(4))) unsigned short ushort4v;
typedef unsigned short u16;
typedef unsigned int u32;

#define MFMA32(a, b, c) __builtin_amdgcn_mfma_f32_16x16x32_bf16((a), (b), (c), 0, 0, 0)

__device__ __forceinline__ u16 f2bf(float f) {
    __hip_bfloat16 h = __float2bfloat16(f);       // RNE; compiler can fuse pairs
    return *reinterpret_cast<u16*>(&h);
}
__device__ __forceinline__ u32 pack2(float a, float b) {
    return ((u32)f2bf(b) << 16) | (u32)f2bf(a);
}

// R10/R13-verified attention tile: swapped QK^T (A=k natural rows, B=q),
// per-lane scalar online softmax, bpermute-built PV B-frag. No LDS scratch.
__device__ __forceinline__ void attn_tile(int tile, int lr, int lg, const int* adr,
                                          const short8* qf,           // [2]
                                          const u16 (*lk)[72],
                                          const u16 (*lvT)[264],
                                          const float* mb, float* ob)
{
    const int nst  = tile + 1;
    const int t_my = 16 * tile + lr;

    float m_ = -1e30f, ls = 0.f;
    f32x4 O[4];
    #pragma unroll
    for (int ht = 0; ht < 4; ++ht) O[ht] = (f32x4){0.f, 0.f, 0.f, 0.f};

    for (int c2 = 0; 2 * c2 < nst; ++c2) {
        // dropout masks early (fly under QK + softmax)
        f32x4 md0 = *(const f32x4*)&mb[(size_t)t_my * 256 + 32 * c2 + 4 * lg];
        f32x4 md1 = *(const f32x4*)&mb[(size_t)t_my * 256 + 32 * c2 + 16 + 4 * lg];

        // QK^T swapped: S[t=lr-col][s = 32c2 + 16sl + 4lg + j]
        f32x4 S0, S1;
        {
            const u16* kr = &lk[16 * (2 * c2) + lr][0];
            short8 kf0 = *(const short8*)&kr[8 * lg];
            short8 kf1 = *(const short8*)&kr[32 + 8 * lg];
            f32x4 a = (f32x4){0.f, 0.f, 0.f, 0.f};
            a = MFMA32(kf0, qf[0], a);
            a = MFMA32(kf1, qf[1], a);
            S0 = a;
        }
        {
            const u16* kr = &lk[16 * (2 * c2 + 1) + lr][0];
            short8 kf0 = *(const short8*)&kr[8 * lg];
            short8 kf1 = *(const short8*)&kr[32 + 8 * lg];
            f32x4 a = (f32x4){0.f, 0.f, 0.f, 0.f};
            a = MFMA32(kf0, qf[0], a);
            a = MFMA32(kf1, qf[1], a);
            S1 = a;
        }

        // scale + causal + chunk max (scalar per lane)
        float cm = m_;
        #pragma unroll
        for (int j = 0; j < 4; ++j) {
            const int sg0 = 32 * c2 + 4 * lg + j;
            const int sg1 = sg0 + 16;
            float L0 = (sg0 <= t_my) ? S0[j] * 0.125f : -1e30f;
            float L1 = (sg1 <= t_my) ? S1[j] * 0.125f : -1e30f;
            S0[j] = L0; S1[j] = L1;
            cm = fmaxf(cm, fmaxf(L0, L1));
        }
        cm = fmaxf(cm, __shfl_xor(cm, 16, 64));
        cm = fmaxf(cm, __shfl_xor(cm, 32, 64));

        const float fs = exp2f((m_ - cm) * 1.44269504f);   // 0 on first chunk
        m_ = cm;

        float cs = 0.f;
        #pragma unroll
        for (int j = 0; j < 4; ++j) {
            float p0 = exp2f((S0[j] - cm) * 1.44269504f);
            float p1 = exp2f((S1[j] - cm) * 1.44269504f);
            S0[j] = p0; S1[j] = p1;
            cs += p0 + p1;
        }
        cs += __shfl_xor(cs, 16, 64);
        cs += __shfl_xor(cs, 32, 64);
        ls = ls * fs + cs;
        #pragma unroll
        for (int ht = 0; ht < 4; ++ht) O[ht] *= fs;

        // dropout (unnormalized P), pack, lane-transpose to PV B-frag
        #pragma unroll
        for (int j = 0; j < 4; ++j) {
            S0[j] = (md0[j] >= 0.25f) ? S0[j] : 0.f;
            S1[j] = (md1[j] >= 0.25f) ? S1[j] : 0.f;
        }
        u32 pk0[2], pk1[2];
        pk0[0] = pack2(S0[0], S0[1]); pk0[1] = pack2(S0[2], S0[3]);
        pk1[0] = pack2(S1[0], S1[1]); pk1[1] = pack2(S1[2], S1[3]);
        union { u32 u[4]; short8 s; } pf;
        #pragma unroll
        for (int e = 0; e < 4; ++e) {
            u32 ca = (u32)__builtin_amdgcn_ds_bpermute(adr[e], (int)pk0[e & 1]);
            u32 cb = (u32)__builtin_amdgcn_ds_bpermute(adr[e], (int)pk1[e & 1]);
            pf.u[e] = (lg >> 1) ? cb : ca;
        }

        #pragma unroll
        for (int ht = 0; ht < 4; ++ht) {
            short8 vf = *(const short8*)&lvT[16 * ht + lr][32 * c2 + 8 * lg];
            O[ht] = MFMA32(vf, pf.s, O[ht]);
        }
    }

    // normalize + store
    const float rf = 1.33333333333f / ls;    // (1/sum) * 1/(1-0.25)
    #pragma unroll
    for (int ht = 0; ht < 4; ++ht) {
        f32x4 o = O[ht] * rf;
        *(f32x4*)&ob[(size_t)t_my * 64 + 16 * ht + 4 * lg] = o;
    }
}

// stage full W^T bf16 into wt: lane l owns row n=l; wave w owns chunks 8(w+8i)
#define STAGE_W(Wm) do {                                                     \
    _Pragma("unroll")                                                        \
    for (int i_ = 0; i_ < 4; ++i_) {                                         \
        const int c0_ = 8 * (w + 8 * i_);                                    \
        short8 t_;                                                           \
        _Pragma("unroll")                                                    \
        for (int j_ = 0; j_ < 8; ++j_)                                       \
            t_[j_] = (short)f2bf((Wm)[(size_t)(c0_ + j_) * 64 + l]);         \
        *(short8*)&wt[l][c0_] = t_;                                          \
    } } while (0)

// One 512-thread block per batch; 8 waves; wave w owns t-tiles {w, 15-w}
// (9 PV chunks each, balanced). R7 projection regime: LDS W^T staging,
// (512,2) -> ~256-reg budget (R7 measured 112, no spills). Attention is the
// lighter R10/R13 machinery. LDS = 104448 B -> 1 block/CU.
__global__ __launch_bounds__(512, 2)
void attn_head_fused(const float* __restrict__ x,
                     const float* __restrict__ Wq,
                     const float* __restrict__ Wk,
                     const float* __restrict__ Wv,
                     const float* __restrict__ dmask,
                     float* __restrict__ out)
{
    __shared__ __align__(16) u16 lk[256][72];       // k [s][h]    36864 B
    __shared__ __align__(16) u16 lvT[64][264];      // v^T [h][s]  33792 B
    __shared__ __align__(16) u16 wt[64][264];       // W^T [n][c]  33792 B

    const int b   = blockIdx.x;
    const int tid = threadIdx.x;
    const int w   = tid >> 6;
    const int l   = tid & 63;
    const int lr  = l & 15;
    const int lg  = l >> 4;

    const int TbA = 16 * w;
    const int TbB = 16 * (15 - w);

    const float* xb = x + (size_t)b * 65536;

    // bpermute transpose addresses (R10/R13-verified)
    int adr[4];
    #pragma unroll
    for (int e = 0; e < 4; ++e) {
        const int lgp = ((8 * lg + 2 * e) & 15) >> 2;
        adr[e] = 4 * (lr + 16 * lgp);
    }

    // ---- x A-fragments for both tiles (reused by all three projections) ----
    short8 af[2][8];
    #pragma unroll
    for (int ti = 0; ti < 2; ++ti) {
        const float* xr = xb + (size_t)((ti ? TbB : TbA) + lr) * 256 + lg * 8;
        #pragma unroll
        for (int ks = 0; ks < 8; ++ks) {
            f32x4 a0 = *(const f32x4*)(xr + ks * 32);
            f32x4 a1 = *(const f32x4*)(xr + ks * 32 + 4);
            short8 f;
            f[0] = (short)f2bf(a0[0]); f[1] = (short)f2bf(a0[1]);
            f[2] = (short)f2bf(a0[2]); f[3] = (short)f2bf(a0[3]);
            f[4] = (short)f2bf(a1[0]); f[5] = (short)f2bf(a1[1]);
            f[6] = (short)f2bf(a1[2]); f[7] = (short)f2bf(a1[3]);
            af[ti][ks] = f;
        }
    }

    f32x4 acc[2][4];

    // ================= k projection (normal operands) =================
    STAGE_W(Wk);
    __syncthreads();                                   // B1
    #pragma unroll
    for (int ti = 0; ti < 2; ++ti)
        #pragma unroll
        for (int nj = 0; nj < 4; ++nj) acc[ti][nj] = (f32x4){0.f,0.f,0.f,0.f};
    #pragma unroll
    for (int ks = 0; ks < 8; ++ks)
        #pragma unroll
        for (int nj = 0; nj < 4; ++nj) {
            short8 bf = *(const short8*)&wt[16 * nj + lr][ks * 32 + lg * 8];
            acc[0][nj] = MFMA32(af[0][ks], bf, acc[0][nj]);
            acc[1][nj] = MFMA32(af[1][ks], bf, acc[1][nj]);
        }
    #pragma unroll
    for (int nj = 0; nj < 4; ++nj) {
        const int n = 16 * nj + lr;
        #pragma unroll
        for (int j = 0; j < 4; ++j) {
            lk[TbA + 4 * lg + j][n] = f2bf(acc[0][nj][j]);
            lk[TbB + 4 * lg + j][n] = f2bf(acc[1][nj][j]);
        }
    }
    __syncthreads();                                   // B2 (wt readers done)

    // ================= v projection (normal operands) =================
    STAGE_W(Wv);
    __syncthreads();                                   // B3
    #pragma unroll
    for (int ti = 0; ti < 2; ++ti)
        #pragma unroll
        for (int nj = 0; nj < 4; ++nj) acc[ti][nj] = (f32x4){0.f,0.f,0.f,0.f};
    #pragma unroll
    for (int ks = 0; ks < 8; ++ks)
        #pragma unroll
        for (int nj = 0; nj < 4; ++nj) {
            short8 bf = *(const short8*)&wt[16 * nj + lr][ks * 32 + lg * 8];
            acc[0][nj] = MFMA32(af[0][ks], bf, acc[0][nj]);
            acc[1][nj] = MFMA32(af[1][ks], bf, acc[1][nj]);
        }
    #pragma unroll
    for (int ti = 0; ti < 2; ++ti) {
        const int s0 = (ti ? TbB : TbA) + 4 * lg;
        #pragma unroll
        for (int nj = 0; nj < 4; ++nj) {
            ushort4v pk;
            pk[0] = f2bf(acc[ti][nj][0]);
            pk[1] = f2bf(acc[ti][nj][1]);
            pk[2] = f2bf(acc[ti][nj][2]);
            pk[3] = f2bf(acc[ti][nj][3]);
            *(ushort4v*)&lvT[16 * nj + lr][s0] = pk;
        }
    }
    __syncthreads();                                   // B4 (wt readers done)

    // ========== q projection (SWAPPED -> per-lane q rows -> bpermute B-frags) ==========
    STAGE_W(Wq);
    __syncthreads();                                   // B5 (also: lk/lvT visible)
    #pragma unroll
    for (int ti = 0; ti < 2; ++ti)
        #pragma unroll
        for (int nj = 0; nj < 4; ++nj) acc[ti][nj] = (f32x4){0.f,0.f,0.f,0.f};
    #pragma unroll
    for (int ks = 0; ks < 8; ++ks)
        #pragma unroll
        for (int nj = 0; nj < 4; ++nj) {
            short8 bf = *(const short8*)&wt[16 * nj + lr][ks * 32 + lg * 8];
            acc[0][nj] = MFMA32(bf, af[0][ks], acc[0][nj]);   // A=W^T, B=x
            acc[1][nj] = MFMA32(bf, af[1][ks], acc[1][nj]);
        }
    short8 qf[2][2];
    #pragma unroll
    for (int ti = 0; ti < 2; ++ti) {
        u32 qk[4][2];
        #pragma unroll
        for (int nj = 0; nj < 4; ++nj) {
            qk[nj][0] = pack2(acc[ti][nj][0], acc[ti][nj][1]);
            qk[nj][1] = pack2(acc[ti][nj][2], acc[ti][nj][3]);
        }
        union { u32 u[4]; short8 s; } q0, q1;
        #pragma unroll
        for (int e = 0; e < 4; ++e) {
            u32 a0 = (u32)__builtin_amdgcn_ds_bpermute(adr[e], (int)qk[0][e & 1]);
            u32 a1 = (u32)__builtin_amdgcn_ds_bpermute(adr[e], (int)qk[1][e & 1]);
            q0.u[e] = (lg >> 1) ? a1 : a0;
            u32 b0 = (u32)__builtin_amdgcn_ds_bpermute(adr[e], (int)qk[2][e & 1]);
            u32 b1 = (u32)__builtin_amdgcn_ds_bpermute(adr[e], (int)qk[3][e & 1]);
            q1.u[e] = (lg >> 1) ? b1 : b0;
        }
        qf[ti][0] = q0.s; qf[ti][1] = q1.s;
    }

    // ================= attention (barrier-free, waves desync) =================
    const float* mb = dmask + (size_t)b * 65536;
    float* ob = out + (size_t)b * 16384;

    attn_tile(w,      lr, lg, adr, qf[0], lk, lvT, mb, ob);
    attn_tile(15 - w, lr, lg, adr, qf[1], lk, lvT, mb, ob);
}

extern "C" void kernel_launch(void* const* d_in, const int* in_sizes, int n_in,
                              void* d_out, int out_size, void* d_ws, size_t ws_size,
                              hipStream_t stream) {
    const float* x  = (const float*)d_in[0];
    const float* Wq = (const float*)d_in[1];
    const float* Wk = (const float*)d_in[2];
    const float* Wv = (const float*)d_in[3];
    const float* dm = (const float*)d_in[4];
    float* outp     = (float*)d_out;
    attn_head_fused<<<dim3(512), dim3(512), 0, stream>>>(x, Wq, Wk, Wv, dm, outp);
}